// Round 1
// baseline (245.030 us; speedup 1.0000x reference)
//
#include <hip/hip_runtime.h>

#define BB 4
#define TT 2048
#define CC 1024
#define HH 16
#define DD 64
#define WIN 256

typedef __attribute__((ext_vector_type(8))) short short8;
typedef __attribute__((ext_vector_type(4))) float floatx4;
typedef unsigned short u16;

typedef __attribute__((address_space(3))) void lds_void;
typedef const __attribute__((address_space(1))) void g_void;

__device__ __forceinline__ void gl_lds16(const u16* g, u16* l) {
    // async DMA global->LDS, 16B/lane; LDS dst = wave-uniform base + lane*16
    __builtin_amdgcn_global_load_lds((g_void*)g, (lds_void*)l, 16, 0, 0);
}

__device__ __forceinline__ float bf2f(u16 u) {
    union { unsigned int i; float f; } v; v.i = ((unsigned int)u) << 16; return v.f;
}
__device__ __forceinline__ u16 f2bf(float f) {
    union { float f; unsigned int i; } v; v.f = f;
    unsigned int x = v.i;
    x += ((x >> 16) & 1u) + 0x7FFFu;   // round-to-nearest-even
    return (u16)(x >> 16);
}

// ---------------- fp32 -> bf16 conversion (all three arrays, one launch) -----
__global__ void cvt_all(const float* __restrict__ x, const float* __restrict__ qw,
                        const float* __restrict__ pw,
                        u16* __restrict__ xb, u16* __restrict__ wb, u16* __restrict__ pwb) {
    int bid = blockIdx.x;
    const float* src; u16* dst; int off;
    if (bid < 4096)      { src = x;  dst = xb;  off = bid; }
    else if (bid < 5632) { src = qw; dst = wb;  off = bid - 4096; }
    else                 { src = pw; dst = pwb; off = bid - 5632; }
    int i = (off * 256 + (int)threadIdx.x) * 8;
    float4 a = *(const float4*)(src + i);
    float4 b = *(const float4*)(src + i + 4);
    u16 o[8] = { f2bf(a.x), f2bf(a.y), f2bf(a.z), f2bf(a.w),
                 f2bf(b.x), f2bf(b.y), f2bf(b.z), f2bf(b.w) };
    *(uint4*)(dst + i) = *(const uint4*)o;
}

// ============================================================================
// gemm_qkv: 256x256 tile, BK=64, 8-phase schedule (T2+T3+T4+T5).
//   512 threads = 8 waves (2M x 4N); per-wave output 128x64; 16 MFMA / phase.
//   LDS 128KB: [buf][half][8192 u16]; half: 0=A(k 0..31) 1=A(k 32..63)
//                                            2=B(k 0..31) 3=B(k 32..63)
//   Each half = 256 rows x 32 cols bf16 = 16 segments (16 rows x 32 cols, 1KB).
//   Within segment: chunk (row, c) [16B] at (row&15)*64B + (c ^ ((row>>1)&3))*16B
//   -> ds_read_b128 fragment reads are bank-conflict-free (measured 0 in the
//      BK=32 predecessor with identical per-segment geometry).
//   DMA lane->global mapping inverts the swizzle (gl_lds writes linearly).
//   Phase p computes (buf, k-half kk, M-quadrant qm); staging of tile t+2
//   overwrites each half one phase after its last read. vmcnt(6) at P4/P8 only
//   (3 half-tiles in flight across barriers, never drained to 0).
// ============================================================================
#define NT_QKV 16

__global__ __launch_bounds__(512, 2) void gemm_qkv(
    const u16* __restrict__ A, const u16* __restrict__ Bw,
    const float* __restrict__ bias,
    u16* __restrict__ Qb, u16* __restrict__ Kb, u16* __restrict__ Vb)
{
    const int K = CC;
    __shared__ u16 lds[2][4][8192];   // 128 KB

    const int tid = threadIdx.x;
    const int wave = tid >> 6, lane = tid & 63;
    const int wm = wave >> 2, wn = wave & 3;     // 2 x 4 wave grid
    const int quad = lane >> 4, l15 = lane & 15;
    const int bN = blockIdx.x * 256, bM = blockIdx.y * 256;

    // staging source addresses: issue0 -> rows 0..127, issue1 -> rows 128..255
    const int n0 = tid, n1 = tid + 512;
    const int r0 = (n0 >> 6) * 16 + ((n0 & 63) >> 2);
    const int r1 = (n1 >> 6) * 16 + ((n1 & 63) >> 2);
    const int c0 = (n0 & 3) ^ ((r0 >> 1) & 3);
    const int c1 = (n1 & 3) ^ ((r1 >> 1) & 3);
    const u16* gA0 = A + (size_t)(bM + r0) * K + c0 * 8;
    const u16* gA1 = A + (size_t)(bM + r1) * K + c1 * 8;
    const u16* gB0 = Bw + (size_t)(bN + r0) * K + c0 * 8;
    const u16* gB1 = Bw + (size_t)(bN + r1) * K + c1 * 8;

    const int rdoff = l15 * 32 + ((quad ^ ((l15 >> 1) & 3)) * 8);

    floatx4 acc[8][4] = {};

#define STG_A(buf, kh, t) do { const int ko = (t) * 64 + (kh) * 32;          \
        gl_lds16(gA0 + ko, &lds[buf][kh][wave * 512]);                       \
        gl_lds16(gA1 + ko, &lds[buf][kh][4096 + wave * 512]); } while (0)
#define STG_B(buf, kh, t) do { const int ko = (t) * 64 + (kh) * 32;          \
        gl_lds16(gB0 + ko, &lds[buf][2 + (kh)][wave * 512]);                 \
        gl_lds16(gB1 + ko, &lds[buf][2 + (kh)][4096 + wave * 512]); } while (0)
#define LDA(buf, kk, qm) do { _Pragma("unroll")                              \
        for (int i = 0; i < 4; ++i)                                          \
            af[i] = *(const short8*)&lds[buf][kk][(wm * 8 + (qm) * 4 + i) * 512 + rdoff]; } while (0)
#define LDB(buf, kk) do { _Pragma("unroll")                                  \
        for (int j = 0; j < 4; ++j)                                          \
            bf[j] = *(const short8*)&lds[buf][2 + (kk)][(wn * 4 + j) * 512 + rdoff]; } while (0)
#define MM(qm) do { __builtin_amdgcn_s_setprio(1); _Pragma("unroll")         \
        for (int i = 0; i < 4; ++i) { _Pragma("unroll")                      \
            for (int j = 0; j < 4; ++j)                                      \
                acc[(qm) * 4 + i][j] = __builtin_amdgcn_mfma_f32_16x16x32_bf16( \
                    af[i], bf[j], acc[(qm) * 4 + i][j], 0, 0, 0); }          \
        __builtin_amdgcn_s_setprio(0); } while (0)
#define BARX() do { asm volatile("" ::: "memory");                           \
        __builtin_amdgcn_s_barrier();                                        \
        asm volatile("" ::: "memory"); } while (0)
#define VM6() asm volatile("s_waitcnt vmcnt(6)" ::: "memory")

    // prologue: tile0 all 4 halves + tile1 {B_k0, A_k0, B_k1} (A_k1 at P1)
    STG_B(0, 0, 0); STG_A(0, 0, 0); STG_B(0, 1, 0); STG_A(0, 1, 0);
    STG_B(1, 0, 1); STG_A(1, 0, 1); STG_B(1, 1, 1);
    VM6();            // 6 outstanding = tile1's 3 halves -> tile0 fully arrived
    BARX();

    for (int ii = 0; ii < NT_QKV / 2; ++ii) {
        const int t0 = 2 * ii, t1 = 2 * ii + 1;
        const int t2 = (t0 + 2 < NT_QKV) ? t0 + 2 : t0;  // tail: restage same data
        const int t3 = (t1 + 2 < NT_QKV) ? t1 + 2 : t1;
        short8 af[4], bf[4];
        // P1: (buf0,k0,qm0)   stage buf1.A_k1 <- t1   (buf1.A_k1 last read prev P8)
        LDA(0, 0, 0); LDB(0, 0); STG_A(1, 1, t1);
        BARX(); MM(0); BARX();
        // P2: (buf0,k0,qm1)   stage buf0.B_k0 <- t2   (B_k0 last read P1)
        LDA(0, 0, 1); STG_B(0, 0, t2);
        BARX(); MM(1); BARX();
        // P3: (buf0,k1,qm0)   stage buf0.A_k0 <- t2   (A_k0 last read P2)
        LDA(0, 1, 0); LDB(0, 1); STG_A(0, 0, t2);
        BARX(); MM(0); BARX();
        // P4: (buf0,k1,qm1)   stage buf0.B_k1 <- t2   (B_k1 last read P3); vmcnt(6)
        LDA(0, 1, 1); STG_B(0, 1, t2); VM6();
        BARX(); MM(1); BARX();
        // P5: (buf1,k0,qm0)   stage buf0.A_k1 <- t2   (A_k1 last read P4)
        LDA(1, 0, 0); LDB(1, 0); STG_A(0, 1, t2);
        BARX(); MM(0); BARX();
        // P6: (buf1,k0,qm1)   stage buf1.B_k0 <- t3   (buf1.B_k0 last read P5)
        LDA(1, 0, 1); STG_B(1, 0, t3);
        BARX(); MM(1); BARX();
        // P7: (buf1,k1,qm0)   stage buf1.A_k0 <- t3   (buf1.A_k0 last read P6)
        LDA(1, 1, 0); LDB(1, 1); STG_A(1, 0, t3);
        BARX(); MM(0); BARX();
        // P8: (buf1,k1,qm1)   stage buf1.B_k1 <- t3   (buf1.B_k1 last read P7); vmcnt(6)
        LDA(1, 1, 1); STG_B(1, 1, t3); VM6();
        BARX(); MM(1); BARX();
    }

#undef STG_A
#undef STG_B
#undef LDA
#undef LDB
#undef MM
#undef BARX
#undef VM6

    // epilogue: +bias, bf16, QKV scatter
#pragma unroll
    for (int mf = 0; mf < 8; ++mf)
#pragma unroll
        for (int nf = 0; nf < 4; ++nf) {
            int col = bN + wn * 64 + nf * 16 + l15;          // 0..3071
            float bv = bias[col];
            int which = col >> 10, rem = col & 1023;
            int h = rem >> 6, d = rem & 63;
            u16* dst = which == 0 ? Qb : (which == 1 ? Kb : Vb);
#pragma unroll
            for (int rg = 0; rg < 4; ++rg) {
                int row = bM + wm * 128 + mf * 16 + quad * 4 + rg;  // 0..8191
                int b = row >> 11, t = row & 2047;
                float v = acc[mf][nf][rg] + bv;
                dst[(((size_t)(b * HH + h)) * TT + t) * DD + d] = f2bf(v);
            }
        }
}

// ---------------- bf16 MFMA GEMM: Out = A @ B^T + bias (fp32 out) ------------
__global__ __launch_bounds__(256) void gemm_proj(
    const u16* __restrict__ A, const u16* __restrict__ Bw,
    const float* __restrict__ bias, float* __restrict__ Out)
{
    const int K = CC;
    __shared__ u16 As[4096];
    __shared__ u16 Bs[4096];
    const int tid = threadIdx.x;
    const int wave = tid >> 6, lane = tid & 63;
    const int wm = wave >> 1, wn = wave & 1;
    const int quad = lane >> 4, l15 = lane & 15;
    const int bN = blockIdx.x * 128, bM = blockIdx.y * 128;

    const int srow0 = wave * 16 + (lane >> 2);
    const int srow1 = (wave + 4) * 16 + (lane >> 2);
    const int schunk = ((lane & 3) ^ ((lane >> 3) & 3)) * 8;
    const u16* gA0 = A + (size_t)(bM + srow0) * K + schunk;
    const u16* gA1 = A + (size_t)(bM + srow1) * K + schunk;
    const u16* gB0 = Bw + (size_t)(bN + srow0) * K + schunk;
    const u16* gB1 = Bw + (size_t)(bN + srow1) * K + schunk;
    u16* lA0 = &As[wave * 512];
    u16* lA1 = &As[(wave + 4) * 512];
    u16* lB0 = &Bs[wave * 512];
    u16* lB1 = &Bs[(wave + 4) * 512];

    const int rdoff = l15 * 32 + ((quad ^ ((l15 >> 1) & 3)) * 8);

    floatx4 acc[4][4] = {};

    for (int k0 = 0; k0 < K; k0 += 32) {
        __syncthreads();
        gl_lds16(gA0 + k0, lA0);
        gl_lds16(gA1 + k0, lA1);
        gl_lds16(gB0 + k0, lB0);
        gl_lds16(gB1 + k0, lB1);
        __syncthreads();
        short8 af[4], bf[4];
#pragma unroll
        for (int i = 0; i < 4; ++i) {
            af[i] = *(const short8*)&As[(wm * 4 + i) * 512 + rdoff];
            bf[i] = *(const short8*)&Bs[(wn * 4 + i) * 512 + rdoff];
        }
#pragma unroll
        for (int mi = 0; mi < 4; ++mi)
#pragma unroll
            for (int ni = 0; ni < 4; ++ni)
                acc[mi][ni] = __builtin_amdgcn_mfma_f32_16x16x32_bf16(af[mi], bf[ni], acc[mi][ni], 0, 0, 0);
    }

#pragma unroll
    for (int mi = 0; mi < 4; ++mi)
#pragma unroll
        for (int ni = 0; ni < 4; ++ni) {
            int col = bN + wn * 64 + ni * 16 + l15;
            float bv = bias[col];
#pragma unroll
            for (int rg = 0; rg < 4; ++rg) {
                int row = bM + wm * 64 + mi * 16 + quad * 4 + rg;
                Out[(size_t)row * CC + col] = acc[mi][ni][rg] + bv;
            }
        }
}

// ---------------- flash attention, MFMA (bf16 in, fp32 acc) ------------------
// Q/K/V: [B*H, T, D] bf16.  Y: [B, T, C] bf16 (transposed for proj GEMM)
// Block: 256 threads = 4 waves; 64 queries/block (16/wave); key chunks of 64.
__global__ __launch_bounds__(256) void attn_mfma(
    const u16* __restrict__ Qb, const u16* __restrict__ Kb, const u16* __restrict__ Vb,
    u16* __restrict__ Y)
{
    __shared__ u16 Ks[64][72];        // K chunk, [j][d], +8 pad
    __shared__ u16 Vt[64][72];        // V chunk transposed [d][j], XOR-swizzled j-blocks
    __shared__ u16 Ps[4][16][72];     // per-wave P round-trip buffer [q][j]

    const int tid = threadIdx.x;
    const int wave = tid >> 6, lane = tid & 63;
    const int quad = lane >> 4, l15 = lane & 15;
    const int q0 = blockIdx.x * 64;
    const int bh = blockIdx.y;
    const int b = bh >> 4, h = bh & 15;
    const u16* Qp = Qb + (size_t)bh * TT * DD;
    const u16* Kp = Kb + (size_t)bh * TT * DD;
    const u16* Vp = Vb + (size_t)bh * TT * DD;
    const int qw = q0 + wave * 16;    // this wave's first query

    // Q A-fragments: m=l15 (query), k=quad*8+j (d), 2 k-steps
    short8 qf[2];
    qf[0] = *(const short8*)&Qp[(size_t)(qw + l15) * DD + quad * 8];
    qf[1] = *(const short8*)&Qp[(size_t)(qw + l15) * DD + 32 + quad * 8];

    float m_i[4] = { -1e30f, -1e30f, -1e30f, -1e30f };
    float l_i[4] = { 0.f, 0.f, 0.f, 0.f };
    floatx4 Oacc[4] = {};             // [dtile]; C layout: row=quad*4+reg, col(d)=dt*16+l15

    const int kb = (q0 >= WIN) ? (q0 - WIN) : 0;
    for (int j0 = kb; j0 < q0 + 64; j0 += 64) {
        __syncthreads();
        // stage K chunk [j][d], vectorized
#pragma unroll
        for (int it = 0; it < 2; ++it) {
            int slot = tid + it * 256;
            int j = slot >> 3, c8 = (slot & 7) << 3;
            *(uint4*)&Ks[j][c8] = *(const uint4*)&Kp[(size_t)(j0 + j) * DD + c8];
        }
        // stage V transposed [d][j], swizzle j-block by d>>3 (conflict-free writes)
#pragma unroll
        for (int it = 0; it < 2; ++it) {
            int slot = tid + it * 256;
            int j = slot >> 3, d0 = (slot & 7) << 3;
            uint4 raw = *(const uint4*)&Vp[(size_t)(j0 + j) * DD + d0];
            const u16* u = (const u16*)&raw;
#pragma unroll
            for (int i = 0; i < 8; ++i) {
                int d = d0 + i;
                int col = (((j >> 3) ^ (d >> 3)) << 3) + (j & 7);
                Vt[d][col] = u[i];
            }
        }
        __syncthreads();

        // ---- S = Q K^T (scaled), 4 n-tiles of 16 keys ----
        floatx4 Sacc[4] = {};
#pragma unroll
        for (int nt = 0; nt < 4; ++nt) {
            short8 kf0 = *(const short8*)&Ks[nt * 16 + l15][quad * 8];
            short8 kf1 = *(const short8*)&Ks[nt * 16 + l15][32 + quad * 8];
            Sacc[nt] = __builtin_amdgcn_mfma_f32_16x16x32_bf16(qf[0], kf0, Sacc[nt], 0, 0, 0);
            Sacc[nt] = __builtin_amdgcn_mfma_f32_16x16x32_bf16(qf[1], kf1, Sacc[nt], 0, 0, 0);
        }

        // ---- mask + scale + chunk row-max ----
        float mc[4] = { -1e30f, -1e30f, -1e30f, -1e30f };
#pragma unroll
        for (int nt = 0; nt < 4; ++nt)
#pragma unroll
            for (int r = 0; r < 4; ++r) {
                int q = qw + quad * 4 + r;
                int j = j0 + nt * 16 + l15;
                float s = (j <= q && (q - j) < WIN) ? Sacc[nt][r] * 0.125f : -1e30f;
                Sacc[nt][r] = s;
                mc[r] = fmaxf(mc[r], s);
            }
#pragma unroll
        for (int m = 1; m < 16; m <<= 1)
#pragma unroll
            for (int r = 0; r < 4; ++r) mc[r] = fmaxf(mc[r], __shfl_xor(mc[r], m, 64));

        // ---- online softmax update ----
        float alpha[4];
#pragma unroll
        for (int r = 0; r < 4; ++r) {
            float mn = fmaxf(m_i[r], mc[r]);
            alpha[r] = __expf(m_i[r] - mn);
            m_i[r] = mn;
        }
        float rs[4] = { 0.f, 0.f, 0.f, 0.f };
#pragma unroll
        for (int nt = 0; nt < 4; ++nt)
#pragma unroll
            for (int r = 0; r < 4; ++r) {
                float s = Sacc[nt][r];
                float p = (s > -1e29f) ? __expf(s - m_i[r]) : 0.f;
                Sacc[nt][r] = p;
                rs[r] += p;
            }
#pragma unroll
        for (int m = 1; m < 16; m <<= 1)
#pragma unroll
            for (int r = 0; r < 4; ++r) rs[r] += __shfl_xor(rs[r], m, 64);
#pragma unroll
        for (int r = 0; r < 4; ++r) l_i[r] = l_i[r] * alpha[r] + rs[r];
#pragma unroll
        for (int dt = 0; dt < 4; ++dt)
#pragma unroll
            for (int r = 0; r < 4; ++r) Oacc[dt][r] *= alpha[r];

        // ---- P (C layout) -> LDS -> A layout; per-wave, no barrier needed ----
#pragma unroll
        for (int nt = 0; nt < 4; ++nt)
#pragma unroll
            for (int r = 0; r < 4; ++r)
                Ps[wave][quad * 4 + r][nt * 16 + l15] = f2bf(Sacc[nt][r]);

        // ---- O += P V ----
#pragma unroll
        for (int ks = 0; ks < 2; ++ks) {
            short8 pf = *(const short8*)&Ps[wave][l15][ks * 32 + quad * 8];
#pragma unroll
            for (int dt = 0; dt < 4; ++dt) {
                int d = dt * 16 + l15;
                int col = (((ks * 4 + quad) ^ (d >> 3)) << 3);
                short8 vf = *(const short8*)&Vt[d][col];
                Oacc[dt] = __builtin_amdgcn_mfma_f32_16x16x32_bf16(pf, vf, Oacc[dt], 0, 0, 0);
            }
        }
    }

    // ---- epilogue: O / l, write Y[b,t,h*64+d] ----
    float inv[4];
#pragma unroll
    for (int r = 0; r < 4; ++r) inv[r] = 1.f / l_i[r];
#pragma unroll
    for (int dt = 0; dt < 4; ++dt)
#pragma unroll
        for (int r = 0; r < 4; ++r) {
            int t = qw + quad * 4 + r;
            int d = dt * 16 + l15;
            Y[((size_t)b * TT + t) * CC + h * DD + d] = f2bf(Oacc[dt][r] * inv[r]);
        }
}

// ---------------- launch ----------------
extern "C" void kernel_launch(void* const* d_in, const int* in_sizes, int n_in,
                              void* d_out, int out_size, void* d_ws, size_t ws_size,
                              hipStream_t stream) {
    const float* x      = (const float*)d_in[0];
    // d_in[1] = attn_mask (bool) — mask structure is analytic, unused
    const float* qkv_w  = (const float*)d_in[2];
    const float* qkv_b  = (const float*)d_in[3];
    const float* proj_w = (const float*)d_in[4];
    const float* proj_b = (const float*)d_in[5];
    float* out = (float*)d_out;

    u16* xb  = (u16*)d_ws;                         // 8192*1024
    u16* wb  = xb  + (size_t)8192 * 1024;          // 3072*1024
    u16* pwb = wb  + (size_t)3072 * 1024;          // 1024*1024
    u16* Qb  = pwb + (size_t)1024 * 1024;          // 64*2048*64
    u16* Kb  = Qb  + (size_t)64 * 2048 * 64;
    u16* Vb  = Kb  + (size_t)64 * 2048 * 64;
    u16* Yb  = Vb  + (size_t)64 * 2048 * 64;       // 8192*1024

    cvt_all<<<6144, 256, 0, stream>>>(x, qkv_w, proj_w, xb, wb, pwb);
    gemm_qkv<<<dim3(12, 32), 512, 0, stream>>>(xb, wb, qkv_b, Qb, Kb, Vb);
    attn_mfma<<<dim3(TT / 64, BB * HH), 256, 0, stream>>>(Qb, Kb, Vb, Yb);
    gemm_proj<<<dim3(8, 64), 256, 0, stream>>>(Yb, pwb, proj_b, out);
}